// Round 1
// baseline (307.588 us; speedup 1.0000x reference)
//
#include <hip/hip_runtime.h>
#include <math.h>

#define NS 5000
#define SS 10
#define KK 20
#define HC 102
#define CAPC 512          // candidate capacity per cell (P(overflow) ~ 0)
#define TRAD2 4674.0f     // r^2 ~ (68.4px)^2: corner-cell quarter-disk mean ~70 >= 20

// ---------------- Kernel 1: bezier points (5000 x 10 x 2) ----------------
__global__ void bezier_kernel(const float* __restrict__ cs, const float* __restrict__ ce,
                              const float* __restrict__ cc, const float* __restrict__ loc,
                              float* __restrict__ pts) {
    int tid = blockIdx.x * 256 + threadIdx.x;
    if (tid >= NS * SS) return;
    int i = tid / SS, j = tid - i * SS;
    float lx = loc[i*2+0], ly = loc[i*2+1];
    float sx = cs[i*2+0] + lx, sy = cs[i*2+1] + ly;
    float ex = ce[i*2+0] + lx, ey = ce[i*2+1] + ly;
    float px = cc[i*2+0] + lx, py = cc[i*2+1] + ly;
    const float dt = 1.0f / 9.0f;          // linspace(0,1,10) step in fp32
    float t = (float)j * dt;
    float omt = 1.0f - t;
    float omt2 = omt * omt, t2 = t * t;
    pts[tid*2+0] = px + omt2*(sx - px) + t2*(ex - px);
    pts[tid*2+1] = py + omt2*(sy - py) + t2*(ey - py);
}

// ---------------- Kernel 2: per-coarse-cell top-20 nearest centers ----------------
// One 64-lane wave per cell. Threshold-filter candidates into LDS, then 20 rounds
// of packed (dist_bits<<32 | idx) wave-min => ascending distance, lower-index ties,
// exactly matching jax.lax.top_k(-D, 20) slot order.
__global__ void __launch_bounds__(64) topk_kernel(const float* __restrict__ loc,
                                                  const float* __restrict__ width,
                                                  int* __restrict__ idcs,
                                                  float* __restrict__ wk) {
    __shared__ float sd[CAPC];
    __shared__ int   si[CAPC];
    __shared__ int   scnt;
    int cell = blockIdx.x;
    int ci = cell / HC, cj = cell - ci * HC;
    int lane = threadIdx.x;
    if (lane == 0) scnt = 0;
    __syncthreads();
    const float dc = 512.0f / 101.0f;      // linspace(0,512,102) step in fp32
    float c0 = (float)ci * dc;             // H-coordinate (compares loc[.,0])
    float c1 = (float)cj * dc;             // W-coordinate (compares loc[.,1])
    for (int n = lane; n < NS; n += 64) {
        float dx = c0 - loc[n*2+0];
        float dy = c1 - loc[n*2+1];
        float d = dx*dx + dy*dy;
        if (d < TRAD2) {
            int pos = atomicAdd(&scnt, 1);
            if (pos < CAPC) { sd[pos] = d; si[pos] = n; }
        }
    }
    __syncthreads();
    int cnt = scnt;
    if (cnt >= KK && cnt <= CAPC) {
        unsigned long long pk[CAPC / 64];
        #pragma unroll
        for (int j = 0; j < CAPC / 64; ++j) {
            int mI = j * 64 + lane;
            if (mI < cnt) {
                unsigned int db = __float_as_uint(sd[mI]);
                pk[j] = ((unsigned long long)db << 32) | (unsigned int)si[mI];
            } else {
                pk[j] = ~0ull;
            }
        }
        for (int k = 0; k < KK; ++k) {
            unsigned long long best = pk[0];
            #pragma unroll
            for (int j = 1; j < CAPC / 64; ++j)
                best = (pk[j] < best) ? pk[j] : best;
            #pragma unroll
            for (int off = 32; off > 0; off >>= 1) {
                unsigned long long o = __shfl_xor(best, off, 64);
                best = (o < best) ? o : best;
            }
            if (lane == 0) {
                int widx = (int)(best & 0xffffffffull);
                idcs[cell*KK + k] = widx;
                wk[cell*KK + k]   = width[widx];
            }
            #pragma unroll
            for (int j = 0; j < CAPC / 64; ++j)
                if (pk[j] == best) pk[j] = ~0ull;
        }
    } else {
        // Exactness fallback (statistically never taken): serial top-K on lane 0.
        if (lane == 0) {
            float bd[KK]; int bi[KK];
            for (int k = 0; k < KK; ++k) { bd[k] = 3.4e38f; bi[k] = 0; }
            for (int n = 0; n < NS; ++n) {
                float dx = c0 - loc[n*2+0];
                float dy = c1 - loc[n*2+1];
                float d = dx*dx + dy*dy;
                if (d < bd[KK-1]) {
                    int p = KK - 1;
                    while (p > 0 && bd[p-1] > d) { bd[p] = bd[p-1]; bi[p] = bi[p-1]; --p; }
                    bd[p] = d; bi[p] = n;
                }
            }
            for (int k = 0; k < KK; ++k) {
                idcs[cell*KK + k] = bi[k];
                wk[cell*KK + k]   = width[bi[k]];
            }
        }
    }
}

// ---------------- Kernel 3: full-res render ----------------
__global__ void __launch_bounds__(256) render_kernel(const float* __restrict__ pts,
                                                     const float* __restrict__ color,
                                                     const int* __restrict__ idcs,
                                                     const float* __restrict__ wk,
                                                     float* __restrict__ out) {
    int x = blockIdx.x * 16 + threadIdx.x;
    int y = blockIdx.y * 16 + threadIdx.y;
    const float df = 512.0f / 511.0f;      // linspace(0,512,512) step in fp32
    float p0 = (float)y * df;              // H-coordinate
    float p1 = (float)x * df;              // W-coordinate
    int cy = (y * 51) >> 8;                // floor(y*102/512), exact vs fp32 ref
    int cx = (x * 51) >> 8;
    const int* mi = idcs + (cy * HC + cx) * KK;

    // jax.image.resize linear: half-pixel centers + edge-normalized == clamped bilinear
    const float sc = 102.0f / 512.0f;      // 0.19921875 exact
    float iny = ((float)y + 0.5f) * sc - 0.5f;
    float inx = ((float)x + 0.5f) * sc - 0.5f;
    float y0f = floorf(iny), x0f = floorf(inx);
    float fy = iny - y0f, fx = inx - x0f;
    int y0 = min(max((int)y0f, 0), HC - 1);
    int y1 = min(max((int)y0f + 1, 0), HC - 1);
    int x0 = min(max((int)x0f, 0), HC - 1);
    int x1 = min(max((int)x0f + 1, 0), HC - 1);
    const float* w00 = wk + (y0 * HC + x0) * KK;
    const float* w01 = wk + (y0 * HC + x1) * KK;
    const float* w10 = wk + (y1 * HC + x0) * KK;
    const float* w11 = wk + (y1 * HC + x1) * KK;

    float m = -INFINITY, s = 0.0f;
    float a0 = 0.0f, a1 = 0.0f, a2 = 0.0f, wa = 0.0f;
    float D = INFINITY;

    #pragma unroll 1
    for (int k = 0; k < KK; ++k) {
        int idx = mi[k];
        const float4* pf = (const float4*)(pts + idx * 20);
        float4 f0 = pf[0], f1 = pf[1], f2 = pf[2], f3 = pf[3], f4 = pf[4];
        float qx[10] = {f0.x, f0.z, f1.x, f1.z, f2.x, f2.z, f3.x, f3.z, f4.x, f4.z};
        float qy[10] = {f0.y, f0.w, f1.y, f1.w, f2.y, f2.w, f3.y, f3.w, f4.y, f4.w};
        float mink = INFINITY;
        #pragma unroll
        for (int sg = 0; sg < 9; ++sg) {
            float ax = qx[sg], ay = qy[sg];
            float bx = qx[sg+1] - ax, by = qy[sg+1] - ay;
            float pax = p0 - ax, pay = p1 - ay;
            float dot = bx * pax + by * pay;
            float bb  = bx * bx + by * by;
            float t = dot / bb;
            t = fminf(fmaxf(t, 0.0f), 1.0f);
            float ccx = ax + t * bx, ccy = ay + t * by;
            float ddx = p0 - ccx, ddy = p1 - ccy;
            float d = ddx * ddx + ddy * ddy;
            mink = fminf(mink, d);
        }
        D = fminf(D, mink);
        float xk = 100000.0f * (1.0f / (1e-8f + mink));  // ref: 1e5 * (1/(1e-8+min))
        float wkv = (1.0f - fy) * ((1.0f - fx) * w00[k] + fx * w01[k])
                  +          fy * ((1.0f - fx) * w10[k] + fx * w11[k]);
        float c0v = color[idx*3+0], c1v = color[idx*3+1], c2v = color[idx*3+2];
        // online softmax (== subtract-max softmax up to rounding)
        if (xk > m) {
            float scl = expf(m - xk);      // m=-inf first iter -> 0
            s  = s  * scl + 1.0f;
            a0 = a0 * scl + c0v;
            a1 = a1 * scl + c1v;
            a2 = a2 * scl + c2v;
            wa = wa * scl + wkv;
            m = xk;
        } else {
            float e = expf(xk - m);
            s  += e;
            a0 += c0v * e;
            a1 += c1v * e;
            a2 += c2v * e;
            wa += wkv * e;
        }
    }
    float inv = 1.0f / s;
    float bs = wa * inv;
    float msk = 1.0f / (1.0f + expf(-(bs - D)));   // jax.nn.sigmoid
    float o0 = a0 * inv * msk + (1.0f - msk) * 0.5f;
    float o1 = a1 * inv * msk + (1.0f - msk) * 0.5f;
    float o2 = a2 * inv * msk + (1.0f - msk) * 0.5f;
    int base = (y * 512 + x) * 3;
    out[base+0] = o0;
    out[base+1] = o1;
    out[base+2] = o2;
}

extern "C" void kernel_launch(void* const* d_in, const int* in_sizes, int n_in,
                              void* d_out, int out_size, void* d_ws, size_t ws_size,
                              hipStream_t stream) {
    const float* cs    = (const float*)d_in[0];  // curve_s (5000,2)
    const float* ce    = (const float*)d_in[1];  // curve_e (5000,2)
    const float* cc    = (const float*)d_in[2];  // curve_c (5000,2)
    const float* color = (const float*)d_in[3];  // color   (5000,3)
    const float* loc   = (const float*)d_in[4];  // location(5000,2)
    const float* width = (const float*)d_in[5];  // width   (5000,1)
    float* out = (float*)d_out;

    float* pts  = (float*)d_ws;                          // 5000*10*2 floats (400 KB)
    int*   idcs = (int*)(pts + NS * SS * 2);             // 102*102*20 ints  (832 KB)
    float* wk   = (float*)((char*)idcs + (size_t)HC * HC * KK * sizeof(int)); // 832 KB

    bezier_kernel<<<(NS * SS + 255) / 256, 256, 0, stream>>>(cs, ce, cc, loc, pts);
    topk_kernel<<<HC * HC, 64, 0, stream>>>(loc, width, idcs, wk);
    render_kernel<<<dim3(512 / 16, 512 / 16), dim3(16, 16), 0, stream>>>(pts, color, idcs, wk, out);
}

// Round 2
// 168.771 us; speedup vs baseline: 1.8225x; 1.8225x over previous
//
#include <hip/hip_runtime.h>
#include <math.h>

#define NS 5000
#define SS 10
#define KK 20
#define HC 102
#define NBIN 32
#define BINW 16.0f
#define CAP 256          // per-cell candidate capacity (P(overflow) ~ 1e-9)

// Wave-level LDS sync: drain LDS ops + compiler ordering. Waves in topk_kernel
// own private LDS slices, so no block-wide barrier is needed (escalation loops
// may diverge between waves).
#define WAVE_SYNC() __asm__ volatile("s_waitcnt lgkmcnt(0)" ::: "memory")

// ---------- Kernel 1: per-stroke bezier points + reciprocal |b|^2 table ----------
__global__ void prep_kernel(const float* __restrict__ cs, const float* __restrict__ ce,
                            const float* __restrict__ cc, const float* __restrict__ loc,
                            float* __restrict__ pts, float* __restrict__ invs) {
    int i = blockIdx.x * 256 + threadIdx.x;
    if (i >= NS) return;
    float lx = loc[i*2+0], ly = loc[i*2+1];
    float sx = cs[i*2+0] + lx, sy = cs[i*2+1] + ly;
    float ex = ce[i*2+0] + lx, ey = ce[i*2+1] + ly;
    float px = cc[i*2+0] + lx, py = cc[i*2+1] + ly;
    float qx[SS], qy[SS];
    #pragma unroll
    for (int j = 0; j < SS; ++j) {
        float t = (float)j * (1.0f / 9.0f);   // linspace(0,1,10) step in fp32
        float omt = 1.0f - t;
        float omt2 = omt * omt, t2 = t * t;
        qx[j] = px + omt2 * (sx - px) + t2 * (ex - px);
        qy[j] = py + omt2 * (sy - py) + t2 * (ey - py);
        pts[(i*SS+j)*2+0] = qx[j];
        pts[(i*SS+j)*2+1] = qy[j];
    }
    #pragma unroll
    for (int sg = 0; sg < 9; ++sg) {
        float bx = qx[sg+1] - qx[sg], by = qy[sg+1] - qy[sg];
        invs[i*12+sg] = 1.0f / (bx*bx + by*by);   // full-precision at prep time
    }
    invs[i*12+9] = 0.0f; invs[i*12+10] = 0.0f; invs[i*12+11] = 0.0f;  // pad to 3x float4
}

// ---------- Kernel 2a: bin counts ----------
__global__ void bincount_kernel(const float* __restrict__ loc, int* __restrict__ binCnt) {
    int i = blockIdx.x * 256 + threadIdx.x;
    if (i >= NS) return;
    int b0 = min(max((int)(loc[i*2+0] * (1.0f/BINW)), 0), NBIN-1);
    int b1 = min(max((int)(loc[i*2+1] * (1.0f/BINW)), 0), NBIN-1);
    atomicAdd(&binCnt[b0*NBIN + b1], 1);
}

// ---------- Kernel 2b: exclusive prefix over 1024 bins (single block) ----------
__global__ void binscan_kernel(const int* __restrict__ binCnt, int* __restrict__ binStart) {
    __shared__ int tmp[NBIN*NBIN];
    int t = threadIdx.x;
    tmp[t] = binCnt[t];
    __syncthreads();
    for (int off = 1; off < NBIN*NBIN; off <<= 1) {
        int v = (t >= off) ? tmp[t - off] : 0;
        __syncthreads();
        tmp[t] += v;
        __syncthreads();
    }
    binStart[t + 1] = tmp[t];          // inclusive -> start[b+1]
    if (t == 0) binStart[0] = 0;
}

// ---------- Kernel 2c: scatter strokes into CSR order ----------
__global__ void binscatter_kernel(const float* __restrict__ loc, const int* __restrict__ binStart,
                                  int* __restrict__ binFill, float2* __restrict__ sxy,
                                  int* __restrict__ sid) {
    int i = blockIdx.x * 256 + threadIdx.x;
    if (i >= NS) return;
    float l0 = loc[i*2+0], l1 = loc[i*2+1];
    int b0 = min(max((int)(l0 * (1.0f/BINW)), 0), NBIN-1);
    int b1 = min(max((int)(l1 * (1.0f/BINW)), 0), NBIN-1);
    int b = b0*NBIN + b1;
    int pos = binStart[b] + atomicAdd(&binFill[b], 1);
    sxy[pos] = make_float2(l0, l1);
    sid[pos] = i;
}

// ---------- Kernel 3: per-cell top-20 via binned window scan ----------
// One wave per cell, 4 cells per 256-thread block. Candidates filtered by d<R^2
// into wave-private LDS, then 20 rounds of packed (dist_bits<<32|idx) wave-min:
// ascending distance, lower-index ties == jax.lax.top_k(-D, K) slot order.
// Exact because: cnt>=20 candidates inside radius R implies the global top-20
// all lie inside R (hence in the candidate set). cnt<20 -> escalate R.
__global__ void __launch_bounds__(256) topk_kernel(const float* __restrict__ loc,
                                                   const float* __restrict__ width,
                                                   const float2* __restrict__ sxy,
                                                   const int* __restrict__ sid,
                                                   const int* __restrict__ binStart,
                                                   int* __restrict__ idcs,
                                                   float* __restrict__ wk) {
    __shared__ float sd[4][CAP];
    __shared__ int   si[4][CAP];
    __shared__ int   scnt[4];
    int w = threadIdx.x >> 6, lane = threadIdx.x & 63;
    int cell = blockIdx.x * 4 + w;
    if (cell >= HC*HC) return;
    int ci = cell / HC, cj = cell - ci * HC;
    const float dc = 512.0f / 101.0f;       // linspace(0,512,102) step in fp32
    float c0 = (float)ci * dc;
    float c1 = (float)cj * dc;

    float R = 40.0f;                        // interior expectation ~96 candidates
    int cnt = 0;
    for (int attempt = 0; attempt < 4; ++attempt) {
        float R2 = R * R;
        if (lane == 0) scnt[w] = 0;
        WAVE_SYNC();
        int by0 = max((int)((c0 - R) * (1.0f/BINW)), 0);
        int by1 = min((int)((c0 + R) * (1.0f/BINW)), NBIN-1);
        int bx0 = max((int)((c1 - R) * (1.0f/BINW)), 0);
        int bx1 = min((int)((c1 + R) * (1.0f/BINW)), NBIN-1);
        for (int by = by0; by <= by1; ++by) {
            int s = binStart[by*NBIN + bx0];
            int e = binStart[by*NBIN + bx1 + 1];     // bins in a row are contiguous
            for (int t = s + lane; t < e; t += 64) {
                float2 p = sxy[t];
                float dx = c0 - p.x, dy = c1 - p.y;
                float d = dx*dx + dy*dy;
                if (d < R2) {
                    int pos = atomicAdd(&scnt[w], 1);
                    if (pos < CAP) { sd[w][pos] = d; si[w][pos] = sid[t]; }
                }
            }
        }
        WAVE_SYNC();
        cnt = scnt[w];
        if (cnt >= KK) break;               // includes overflow (cnt>CAP) -> fallback below
        R *= 1.6f;
    }

    if (cnt >= KK && cnt <= CAP) {
        unsigned long long pk[4];
        #pragma unroll
        for (int j = 0; j < 4; ++j) {
            int mI = j*64 + lane;
            pk[j] = (mI < cnt)
                ? ((unsigned long long)__float_as_uint(sd[w][mI]) << 32) | (unsigned int)si[w][mI]
                : ~0ull;
        }
        for (int k = 0; k < KK; ++k) {
            unsigned long long best = pk[0];
            best = pk[1] < best ? pk[1] : best;
            best = pk[2] < best ? pk[2] : best;
            best = pk[3] < best ? pk[3] : best;
            #pragma unroll
            for (int off = 32; off > 0; off >>= 1) {
                unsigned long long o = __shfl_xor(best, off, 64);
                best = (o < best) ? o : best;
            }
            if (lane == 0) {
                int widx = (int)(best & 0xffffffffull);
                idcs[cell*KK + k] = widx;
                wk[cell*KK + k]   = width[widx];
            }
            #pragma unroll
            for (int j = 0; j < 4; ++j)
                if (pk[j] == best) pk[j] = ~0ull;
        }
    } else {
        // Exactness fallback (statistically never taken): serial top-K on lane 0.
        if (lane == 0) {
            float bd[KK]; int bi[KK];
            for (int k = 0; k < KK; ++k) { bd[k] = 3.4e38f; bi[k] = 0; }
            for (int n = 0; n < NS; ++n) {
                float dx = c0 - loc[n*2+0];
                float dy = c1 - loc[n*2+1];
                float d = dx*dx + dy*dy;
                if (d < bd[KK-1]) {
                    int p = KK - 1;
                    while (p > 0 && bd[p-1] > d) { bd[p] = bd[p-1]; bi[p] = bi[p-1]; --p; }
                    bd[p] = d; bi[p] = n;
                }
            }
            for (int k = 0; k < KK; ++k) {
                idcs[cell*KK + k] = bi[k];
                wk[cell*KK + k]   = width[bi[k]];
            }
        }
    }
}

// ---------- Kernel 4: full-res render (fast rcp table + __expf) ----------
__global__ void __launch_bounds__(256) render_kernel(const float* __restrict__ pts,
                                                     const float* __restrict__ invs,
                                                     const float* __restrict__ color,
                                                     const int* __restrict__ idcs,
                                                     const float* __restrict__ wk,
                                                     float* __restrict__ out) {
    int x = blockIdx.x * 64 + threadIdx.x;   // wave = 64 contiguous x pixels
    int y = blockIdx.y * 4  + threadIdx.y;
    const float df = 512.0f / 511.0f;        // linspace(0,512,512) step in fp32
    float p0 = (float)y * df;                // H-coordinate
    float p1 = (float)x * df;                // W-coordinate
    int cy = (y * 51) >> 8;                  // floor(y*102/512), exact vs fp32 ref
    int cx = (x * 51) >> 8;
    const int* mi = idcs + (cy * HC + cx) * KK;

    // jax.image.resize linear: half-pixel centers + edge-normalized == clamped bilinear
    const float sc = 102.0f / 512.0f;        // exact in fp32
    float iny = ((float)y + 0.5f) * sc - 0.5f;
    float inx = ((float)x + 0.5f) * sc - 0.5f;
    float y0f = floorf(iny), x0f = floorf(inx);
    float fy = iny - y0f, fx = inx - x0f;
    int y0 = min(max((int)y0f, 0), HC - 1);
    int y1 = min(max((int)y0f + 1, 0), HC - 1);
    int x0 = min(max((int)x0f, 0), HC - 1);
    int x1 = min(max((int)x0f + 1, 0), HC - 1);
    const float* w00 = wk + (y0 * HC + x0) * KK;
    const float* w01 = wk + (y0 * HC + x1) * KK;
    const float* w10 = wk + (y1 * HC + x0) * KK;
    const float* w11 = wk + (y1 * HC + x1) * KK;

    float m = -INFINITY, s = 0.0f;
    float a0 = 0.0f, a1 = 0.0f, a2 = 0.0f, wa = 0.0f;
    float D = INFINITY;

    #pragma unroll 1
    for (int k = 0; k < KK; ++k) {
        int idx = mi[k];
        const float4* pf = (const float4*)(pts  + idx * 20);
        const float4* vf = (const float4*)(invs + idx * 12);
        float4 f0 = pf[0], f1 = pf[1], f2 = pf[2], f3 = pf[3], f4 = pf[4];
        float4 i0 = vf[0], i1 = vf[1], i2 = vf[2];
        float qx[10] = {f0.x, f0.z, f1.x, f1.z, f2.x, f2.z, f3.x, f3.z, f4.x, f4.z};
        float qy[10] = {f0.y, f0.w, f1.y, f1.w, f2.y, f2.w, f3.y, f3.w, f4.y, f4.w};
        float iv[9]  = {i0.x, i0.y, i0.z, i0.w, i1.x, i1.y, i1.z, i1.w, i2.x};
        float mink = INFINITY;
        #pragma unroll
        for (int sg = 0; sg < 9; ++sg) {
            float ax = qx[sg], ay = qy[sg];
            float bx = qx[sg+1] - ax, by = qy[sg+1] - ay;
            float pax = p0 - ax, pay = p1 - ay;
            float dot = bx * pax + by * pay;
            float t = dot * iv[sg];
            t = fminf(fmaxf(t, 0.0f), 1.0f);
            float ccx = ax + t * bx, ccy = ay + t * by;
            float ddx = p0 - ccx, ddy = p1 - ccy;
            float d = ddx * ddx + ddy * ddy;
            mink = fminf(mink, d);
        }
        D = fminf(D, mink);
        float xk = 100000.0f / (1e-8f + mink);   // ref: 1e5 * (1/(1e-8+min))
        float wkv = (1.0f - fy) * ((1.0f - fx) * w00[k] + fx * w01[k])
                  +          fy * ((1.0f - fx) * w10[k] + fx * w11[k]);
        float c0v = color[idx*3+0], c1v = color[idx*3+1], c2v = color[idx*3+2];
        // online softmax (== subtract-max softmax up to rounding)
        if (xk > m) {
            float scl = __expf(m - xk);          // m=-inf first iter -> 0
            s  = s  * scl + 1.0f;
            a0 = a0 * scl + c0v;
            a1 = a1 * scl + c1v;
            a2 = a2 * scl + c2v;
            wa = wa * scl + wkv;
            m = xk;
        } else {
            float e = __expf(xk - m);
            s  += e;
            a0 += c0v * e;
            a1 += c1v * e;
            a2 += c2v * e;
            wa += wkv * e;
        }
    }
    float inv = 1.0f / s;
    float bs = wa * inv;
    float msk = 1.0f / (1.0f + __expf(-(bs - D)));   // sigmoid
    float o0 = a0 * inv * msk + (1.0f - msk) * 0.5f;
    float o1 = a1 * inv * msk + (1.0f - msk) * 0.5f;
    float o2 = a2 * inv * msk + (1.0f - msk) * 0.5f;
    int base = (y * 512 + x) * 3;
    out[base+0] = o0;
    out[base+1] = o1;
    out[base+2] = o2;
}

extern "C" void kernel_launch(void* const* d_in, const int* in_sizes, int n_in,
                              void* d_out, int out_size, void* d_ws, size_t ws_size,
                              hipStream_t stream) {
    const float* cs    = (const float*)d_in[0];  // curve_s (5000,2)
    const float* ce    = (const float*)d_in[1];  // curve_e (5000,2)
    const float* cc    = (const float*)d_in[2];  // curve_c (5000,2)
    const float* color = (const float*)d_in[3];  // color   (5000,3)
    const float* loc   = (const float*)d_in[4];  // location(5000,2)
    const float* width = (const float*)d_in[5];  // width   (5000,1)
    float* out = (float*)d_out;

    char* p = (char*)d_ws;
    float*  pts      = (float*)p;                 p += NS * SS * 2 * sizeof(float);   // 400000
    float*  invs     = (float*)p;                 p += NS * 12 * sizeof(float);       // 240000
    int*    idcs     = (int*)p;                   p += (size_t)HC*HC*KK*sizeof(int);  // 832320
    float*  wk       = (float*)p;                 p += (size_t)HC*HC*KK*sizeof(float);// 832320
    int*    binCnt   = (int*)p;                   p += NBIN*NBIN*sizeof(int);         // 4096
    int*    binFill  = (int*)p;                   p += NBIN*NBIN*sizeof(int);         // 4096
    int*    binStart = (int*)p;                   p += 4112;                          // 1025 ints + pad
    float2* sxy      = (float2*)p;                p += NS * sizeof(float2);           // 40000
    int*    sid      = (int*)p;                   /* 20000 */

    hipMemsetAsync(binCnt, 0, 2 * NBIN * NBIN * sizeof(int), stream);  // binCnt + binFill

    prep_kernel      <<<(NS + 255) / 256, 256, 0, stream>>>(cs, ce, cc, loc, pts, invs);
    bincount_kernel  <<<(NS + 255) / 256, 256, 0, stream>>>(loc, binCnt);
    binscan_kernel   <<<1, NBIN*NBIN, 0, stream>>>(binCnt, binStart);
    binscatter_kernel<<<(NS + 255) / 256, 256, 0, stream>>>(loc, binStart, binFill, sxy, sid);
    topk_kernel      <<<(HC*HC + 3) / 4, 256, 0, stream>>>(loc, width, sxy, sid, binStart, idcs, wk);
    render_kernel    <<<dim3(512/64, 512/4), dim3(64, 4), 0, stream>>>(pts, invs, color, idcs, wk, out);
}

// Round 5
// 135.661 us; speedup vs baseline: 2.2673x; 1.2441x over previous
//
#include <hip/hip_runtime.h>
#include <math.h>

#define NS 5000
#define SS 10
#define KK 20
#define HC 102
#define NBIN 32
#define BINW 16.0f
#define CAP 192          // per-wave candidate capacity (P(overflow) ~ 0 at R<=48)

// Wave-level LDS sync: drain LDS ops + compiler ordering. Waves own private
// LDS slices; no block barrier needed (escalation may diverge between waves).
#define WAVE_SYNC() __asm__ volatile("s_waitcnt lgkmcnt(0)" ::: "memory")

// ---------- Kernel 1: bezier points + 1/|b|^2 table + bin counts (fused) ----------
__global__ void prep_kernel(const float* __restrict__ cs, const float* __restrict__ ce,
                            const float* __restrict__ cc, const float* __restrict__ loc,
                            float* __restrict__ pts, float* __restrict__ invs,
                            int* __restrict__ binCnt) {
    int i = blockIdx.x * 256 + threadIdx.x;
    if (i >= NS) return;
    float lx = loc[i*2+0], ly = loc[i*2+1];
    float sx = cs[i*2+0] + lx, sy = cs[i*2+1] + ly;
    float ex = ce[i*2+0] + lx, ey = ce[i*2+1] + ly;
    float px = cc[i*2+0] + lx, py = cc[i*2+1] + ly;
    float qx[SS], qy[SS];
    #pragma unroll
    for (int j = 0; j < SS; ++j) {
        float t = (float)j * (1.0f / 9.0f);   // linspace(0,1,10) step in fp32
        float omt = 1.0f - t;
        float omt2 = omt * omt, t2 = t * t;
        qx[j] = px + omt2 * (sx - px) + t2 * (ex - px);
        qy[j] = py + omt2 * (sy - py) + t2 * (ey - py);
        pts[(i*SS+j)*2+0] = qx[j];
        pts[(i*SS+j)*2+1] = qy[j];
    }
    #pragma unroll
    for (int sg = 0; sg < 9; ++sg) {
        float bx = qx[sg+1] - qx[sg], by = qy[sg+1] - qy[sg];
        invs[i*12+sg] = 1.0f / (bx*bx + by*by);   // full precision at prep time
    }
    invs[i*12+9] = 0.0f; invs[i*12+10] = 0.0f; invs[i*12+11] = 0.0f;  // pad to 3x float4
    int b0 = min(max((int)(lx * (1.0f/BINW)), 0), NBIN-1);
    int b1 = min(max((int)(ly * (1.0f/BINW)), 0), NBIN-1);
    atomicAdd(&binCnt[b0*NBIN + b1], 1);
}

// ---------- Kernel 2a: exclusive prefix over 1024 bins (single block) ----------
__global__ void binscan_kernel(const int* __restrict__ binCnt, int* __restrict__ binStart) {
    __shared__ int tmp[NBIN*NBIN];
    int t = threadIdx.x;
    tmp[t] = binCnt[t];
    __syncthreads();
    for (int off = 1; off < NBIN*NBIN; off <<= 1) {
        int v = (t >= off) ? tmp[t - off] : 0;
        __syncthreads();
        tmp[t] += v;
        __syncthreads();
    }
    binStart[t + 1] = tmp[t];          // inclusive -> start[b+1]
    if (t == 0) binStart[0] = 0;
}

// ---------- Kernel 2b: scatter strokes into CSR order ----------
__global__ void binscatter_kernel(const float* __restrict__ loc, const int* __restrict__ binStart,
                                  int* __restrict__ binFill, float2* __restrict__ sxy,
                                  int* __restrict__ sid) {
    int i = blockIdx.x * 256 + threadIdx.x;
    if (i >= NS) return;
    float l0 = loc[i*2+0], l1 = loc[i*2+1];
    int b0 = min(max((int)(l0 * (1.0f/BINW)), 0), NBIN-1);
    int b1 = min(max((int)(l1 * (1.0f/BINW)), 0), NBIN-1);
    int b = b0*NBIN + b1;
    int pos = binStart[b] + atomicAdd(&binFill[b], 1);
    sxy[pos] = make_float2(l0, l1);
    sid[pos] = i;
}

// ---------- Kernel 3: per-cell top-20 via ballot compaction + rank selection ----------
// One wave per cell, 4 cells/block (grid = HC*HC/4 = 2601 exactly). Candidates
// with d<R^2 are ballot-compacted into wave-private LDS as (dist_bits<<32|idx)
// keys. Each lane computes its key's exact rank (# smaller keys) with an
// independent-iteration broadcast-read loop; ranks are a permutation (keys
// unique via idx low bits), so rank<20 lanes scatter straight to the output
// slot. Ascending distance, lower-index ties == jax.lax.top_k(-D, K) order.
// Exact: cnt>=20 inside radius R implies the global top-20 lie inside R.
__global__ void __launch_bounds__(256) topk_kernel(const float* __restrict__ loc,
                                                   const float* __restrict__ width,
                                                   const float2* __restrict__ sxy,
                                                   const int* __restrict__ sid,
                                                   const int* __restrict__ binStart,
                                                   int* __restrict__ idcs,
                                                   float* __restrict__ wk) {
    __shared__ unsigned long long sk[4][CAP];
    int w = threadIdx.x >> 6, lane = threadIdx.x & 63;
    int cell = blockIdx.x * 4 + w;                 // grid covers exactly HC*HC
    int ci = cell / HC, cj = cell - ci * HC;
    const float dc = 512.0f / 101.0f;              // linspace(0,512,102) step in fp32
    float c0 = (float)ci * dc;
    float c1 = (float)cj * dc;
    unsigned long long below = (1ull << lane) - 1ull;

    float R = 30.0f;                               // interior E[cnt] ~ 54
    int cnt = 0;
    for (int attempt = 0; attempt < 5; ++attempt) {
        float R2 = R * R;
        int base = 0;
        int by0 = max((int)((c0 - R) * (1.0f/BINW)), 0);
        int by1 = min((int)((c0 + R) * (1.0f/BINW)), NBIN-1);
        int bx0 = max((int)((c1 - R) * (1.0f/BINW)), 0);
        int bx1 = min((int)((c1 + R) * (1.0f/BINW)), NBIN-1);
        for (int by = by0; by <= by1; ++by) {
            int s = binStart[by*NBIN + bx0];
            int e = binStart[by*NBIN + bx1 + 1];   // bins in a row are contiguous
            for (int t0 = s; t0 < e; t0 += 64) {
                int t = t0 + lane;
                int tc = min(t, e - 1);
                float2 p = sxy[tc];
                float dx = c0 - p.x, dy = c1 - p.y;
                float d = dx*dx + dy*dy;
                bool pred = (t < e) && (d < R2);
                unsigned long long mask = __ballot(pred);
                int pos = base + __popcll(mask & below);
                if (pred && pos < CAP)
                    sk[w][pos] = ((unsigned long long)__float_as_uint(d) << 32)
                               | (unsigned int)sid[tc];
                base += __popcll(mask);
            }
        }
        cnt = base;
        if (cnt >= KK) break;                      // includes overflow -> fallback below
        R *= 1.6f;
    }
    WAVE_SYNC();

    if (cnt >= KK && cnt <= CAP) {
        if (cnt <= 64) {
            // common path (~92%): one key per lane
            unsigned long long k0 = (lane < cnt) ? sk[w][lane] : ~0ull;
            int r0 = 0;
            int j = 0;
            #pragma unroll 1
            for (; j + 4 <= cnt; j += 4) {
                unsigned long long a = sk[w][j],   b = sk[w][j+1];
                unsigned long long c = sk[w][j+2], d = sk[w][j+3];
                r0 += (int)(a < k0) + (int)(b < k0) + (int)(c < k0) + (int)(d < k0);
            }
            for (; j < cnt; ++j) r0 += (int)(sk[w][j] < k0);
            if (r0 < KK && lane < cnt) {
                int idx = (int)(unsigned int)(k0 & 0xffffffffull);
                idcs[cell*KK + r0] = idx;
                wk[cell*KK + r0]   = width[idx];
            }
        } else {
            // up to 3 keys per lane
            unsigned long long k0 = (lane       < cnt) ? sk[w][lane]       : ~0ull;
            unsigned long long k1 = (lane + 64  < cnt) ? sk[w][lane + 64]  : ~0ull;
            unsigned long long k2 = (lane + 128 < cnt) ? sk[w][lane + 128] : ~0ull;
            int r0 = 0, r1 = 0, r2 = 0;
            #pragma unroll 1
            for (int j = 0; j < cnt; ++j) {
                unsigned long long a = sk[w][j];
                r0 += (int)(a < k0); r1 += (int)(a < k1); r2 += (int)(a < k2);
            }
            if (r0 < KK && lane < cnt) {
                int idx = (int)(unsigned int)(k0 & 0xffffffffull);
                idcs[cell*KK + r0] = idx;  wk[cell*KK + r0] = width[idx];
            }
            if (r1 < KK && lane + 64 < cnt) {
                int idx = (int)(unsigned int)(k1 & 0xffffffffull);
                idcs[cell*KK + r1] = idx;  wk[cell*KK + r1] = width[idx];
            }
            if (r2 < KK && lane + 128 < cnt) {
                int idx = (int)(unsigned int)(k2 & 0xffffffffull);
                idcs[cell*KK + r2] = idx;  wk[cell*KK + r2] = width[idx];
            }
        }
    } else {
        // Exactness fallback (statistically never taken): serial top-K on lane 0.
        if (lane == 0) {
            float bd[KK]; int bi[KK];
            for (int k = 0; k < KK; ++k) { bd[k] = 3.4e38f; bi[k] = 0; }
            for (int n = 0; n < NS; ++n) {
                float dx = c0 - loc[n*2+0];
                float dy = c1 - loc[n*2+1];
                float d = dx*dx + dy*dy;
                if (d < bd[KK-1]) {
                    int p = KK - 1;
                    while (p > 0 && bd[p-1] > d) { bd[p] = bd[p-1]; bi[p] = bi[p-1]; --p; }
                    bd[p] = d; bi[p] = n;
                }
            }
            for (int k = 0; k < KK; ++k) {
                idcs[cell*KK + k] = bi[k];
                wk[cell*KK + k]   = width[bi[k]];
            }
        }
    }
}

// ---------- Kernel 4: full-res render (fast rcp table + __expf) ----------
__global__ void __launch_bounds__(256) render_kernel(const float* __restrict__ pts,
                                                     const float* __restrict__ invs,
                                                     const float* __restrict__ color,
                                                     const int* __restrict__ idcs,
                                                     const float* __restrict__ wk,
                                                     float* __restrict__ out) {
    int x = blockIdx.x * 64 + threadIdx.x;   // wave = 64 contiguous x pixels
    int y = blockIdx.y * 4  + threadIdx.y;
    const float df = 512.0f / 511.0f;        // linspace(0,512,512) step in fp32
    float p0 = (float)y * df;                // H-coordinate
    float p1 = (float)x * df;                // W-coordinate
    int cy = (y * 51) >> 8;                  // floor(y*102/512), exact vs fp32 ref
    int cx = (x * 51) >> 8;
    const int* mi = idcs + (cy * HC + cx) * KK;

    // jax.image.resize linear: half-pixel centers + edge-normalized == clamped bilinear
    const float sc = 102.0f / 512.0f;        // exact in fp32
    float iny = ((float)y + 0.5f) * sc - 0.5f;
    float inx = ((float)x + 0.5f) * sc - 0.5f;
    float y0f = floorf(iny), x0f = floorf(inx);
    float fy = iny - y0f, fx = inx - x0f;
    int y0 = min(max((int)y0f, 0), HC - 1);
    int y1 = min(max((int)y0f + 1, 0), HC - 1);
    int x0 = min(max((int)x0f, 0), HC - 1);
    int x1 = min(max((int)x0f + 1, 0), HC - 1);
    const float* w00 = wk + (y0 * HC + x0) * KK;
    const float* w01 = wk + (y0 * HC + x1) * KK;
    const float* w10 = wk + (y1 * HC + x0) * KK;
    const float* w11 = wk + (y1 * HC + x1) * KK;

    float m = -INFINITY, s = 0.0f;
    float a0 = 0.0f, a1 = 0.0f, a2 = 0.0f, wa = 0.0f;
    float D = INFINITY;

    #pragma unroll 1
    for (int k = 0; k < KK; ++k) {
        int idx = mi[k];
        const float4* pf = (const float4*)(pts  + idx * 20);
        const float4* vf = (const float4*)(invs + idx * 12);
        float4 f0 = pf[0], f1 = pf[1], f2 = pf[2], f3 = pf[3], f4 = pf[4];
        float4 i0 = vf[0], i1 = vf[1], i2 = vf[2];
        float qx[10] = {f0.x, f0.z, f1.x, f1.z, f2.x, f2.z, f3.x, f3.z, f4.x, f4.z};
        float qy[10] = {f0.y, f0.w, f1.y, f1.w, f2.y, f2.w, f3.y, f3.w, f4.y, f4.w};
        float iv[9]  = {i0.x, i0.y, i0.z, i0.w, i1.x, i1.y, i1.z, i1.w, i2.x};
        float mink = INFINITY;
        #pragma unroll
        for (int sg = 0; sg < 9; ++sg) {
            float ax = qx[sg], ay = qy[sg];
            float bx = qx[sg+1] - ax, by = qy[sg+1] - ay;
            float pax = p0 - ax, pay = p1 - ay;
            float dot = bx * pax + by * pay;
            float t = dot * iv[sg];
            t = fminf(fmaxf(t, 0.0f), 1.0f);
            float ccx = ax + t * bx, ccy = ay + t * by;
            float ddx = p0 - ccx, ddy = p1 - ccy;
            float d = ddx * ddx + ddy * ddy;
            mink = fminf(mink, d);
        }
        D = fminf(D, mink);
        float xk = 100000.0f / (1e-8f + mink);   // ref: 1e5 * (1/(1e-8+min))
        float wkv = (1.0f - fy) * ((1.0f - fx) * w00[k] + fx * w01[k])
                  +          fy * ((1.0f - fx) * w10[k] + fx * w11[k]);
        float c0v = color[idx*3+0], c1v = color[idx*3+1], c2v = color[idx*3+2];
        // online softmax (== subtract-max softmax up to rounding)
        if (xk > m) {
            float scl = __expf(m - xk);          // m=-inf first iter -> 0
            s  = s  * scl + 1.0f;
            a0 = a0 * scl + c0v;
            a1 = a1 * scl + c1v;
            a2 = a2 * scl + c2v;
            wa = wa * scl + wkv;
            m = xk;
        } else {
            float e = __expf(xk - m);
            s  += e;
            a0 += c0v * e;
            a1 += c1v * e;
            a2 += c2v * e;
            wa += wkv * e;
        }
    }
    float inv = 1.0f / s;
    float bs = wa * inv;
    float msk = 1.0f / (1.0f + __expf(-(bs - D)));   // sigmoid
    float o0 = a0 * inv * msk + (1.0f - msk) * 0.5f;
    float o1 = a1 * inv * msk + (1.0f - msk) * 0.5f;
    float o2 = a2 * inv * msk + (1.0f - msk) * 0.5f;
    int base = (y * 512 + x) * 3;
    out[base+0] = o0;
    out[base+1] = o1;
    out[base+2] = o2;
}

extern "C" void kernel_launch(void* const* d_in, const int* in_sizes, int n_in,
                              void* d_out, int out_size, void* d_ws, size_t ws_size,
                              hipStream_t stream) {
    const float* cs    = (const float*)d_in[0];  // curve_s (5000,2)
    const float* ce    = (const float*)d_in[1];  // curve_e (5000,2)
    const float* cc    = (const float*)d_in[2];  // curve_c (5000,2)
    const float* color = (const float*)d_in[3];  // color   (5000,3)
    const float* loc   = (const float*)d_in[4];  // location(5000,2)
    const float* width = (const float*)d_in[5];  // width   (5000,1)
    float* out = (float*)d_out;

    char* p = (char*)d_ws;
    float*  pts      = (float*)p;                 p += NS * SS * 2 * sizeof(float);   // 400000
    float*  invs     = (float*)p;                 p += NS * 12 * sizeof(float);       // 240000
    int*    idcs     = (int*)p;                   p += (size_t)HC*HC*KK*sizeof(int);  // 832320
    float*  wk       = (float*)p;                 p += (size_t)HC*HC*KK*sizeof(float);// 832320
    int*    binCnt   = (int*)p;                   p += NBIN*NBIN*sizeof(int);         // 4096
    int*    binFill  = (int*)p;                   p += NBIN*NBIN*sizeof(int);         // 4096
    int*    binStart = (int*)p;                   p += 4112;                          // 1025 ints + pad
    float2* sxy      = (float2*)p;                p += NS * sizeof(float2);           // 40000
    int*    sid      = (int*)p;                   /* 20000 */

    hipMemsetAsync(binCnt, 0, 2 * NBIN * NBIN * sizeof(int), stream);  // binCnt + binFill

    prep_kernel      <<<(NS + 255) / 256, 256, 0, stream>>>(cs, ce, cc, loc, pts, invs, binCnt);
    binscan_kernel   <<<1, NBIN*NBIN, 0, stream>>>(binCnt, binStart);
    binscatter_kernel<<<(NS + 255) / 256, 256, 0, stream>>>(loc, binStart, binFill, sxy, sid);
    topk_kernel      <<<(HC*HC)/4, 256, 0, stream>>>(loc, width, sxy, sid, binStart, idcs, wk);
    render_kernel    <<<dim3(512/64, 512/4), dim3(64, 4), 0, stream>>>(pts, invs, color, idcs, wk, out);
}

// Round 6
// 134.475 us; speedup vs baseline: 2.2873x; 1.0088x over previous
//
#include <hip/hip_runtime.h>
#include <math.h>

#define NS 5000
#define SS 10
#define KK 20
#define HC 102
#define NBIN 32
#define BINW 16.0f
#define CAP 192          // per-wave candidate capacity (P(overflow) ~ 0 at R<=48)

// Wave-level LDS sync: drain LDS ops + compiler ordering. Waves own private
// LDS slices; no block barrier needed (escalation may diverge between waves).
#define WAVE_SYNC() __asm__ volatile("s_waitcnt lgkmcnt(0)" ::: "memory")

// ---------- Kernel 1: packed stroke data + color table + bin counts ----------
// sdata[i][0..19]  = bezier pts interleaved x,y (10 points)
// sdata[i][20..28] = 1/|seg|^2 for 9 segments, [29..31] pad
// ctab[i]          = (r,g,b,width)
__global__ void prep_kernel(const float* __restrict__ cs, const float* __restrict__ ce,
                            const float* __restrict__ cc, const float* __restrict__ loc,
                            const float* __restrict__ color, const float* __restrict__ width,
                            float* __restrict__ sdata, float4* __restrict__ ctab,
                            int* __restrict__ binCnt) {
    int i = blockIdx.x * 256 + threadIdx.x;
    if (i >= NS) return;
    float lx = loc[i*2+0], ly = loc[i*2+1];
    float sx = cs[i*2+0] + lx, sy = cs[i*2+1] + ly;
    float ex = ce[i*2+0] + lx, ey = ce[i*2+1] + ly;
    float px = cc[i*2+0] + lx, py = cc[i*2+1] + ly;
    float qx[SS], qy[SS];
    #pragma unroll
    for (int j = 0; j < SS; ++j) {
        float t = (float)j * (1.0f / 9.0f);   // linspace(0,1,10) step in fp32
        float omt = 1.0f - t;
        float omt2 = omt * omt, t2 = t * t;
        qx[j] = px + omt2 * (sx - px) + t2 * (ex - px);
        qy[j] = py + omt2 * (sy - py) + t2 * (ey - py);
        sdata[i*32 + 2*j + 0] = qx[j];
        sdata[i*32 + 2*j + 1] = qy[j];
    }
    #pragma unroll
    for (int sg = 0; sg < 9; ++sg) {
        float bx = qx[sg+1] - qx[sg], by = qy[sg+1] - qy[sg];
        sdata[i*32 + 20 + sg] = 1.0f / (bx*bx + by*by);   // full precision at prep time
    }
    sdata[i*32 + 29] = 0.0f; sdata[i*32 + 30] = 0.0f; sdata[i*32 + 31] = 0.0f;
    ctab[i] = make_float4(color[i*3+0], color[i*3+1], color[i*3+2], width[i]);
    int b0 = min(max((int)(lx * (1.0f/BINW)), 0), NBIN-1);
    int b1 = min(max((int)(ly * (1.0f/BINW)), 0), NBIN-1);
    atomicAdd(&binCnt[b0*NBIN + b1], 1);
}

// ---------- Kernel 2a: exclusive prefix over 1024 bins (1 barrier) ----------
// 256 threads, 4 bins/thread serial, shuffle wave-scan, 4-entry cross-wave fixup.
__global__ void binscan_kernel(const int* __restrict__ binCnt, int* __restrict__ binStart) {
    __shared__ int wsum[4];
    int t = threadIdx.x;                 // 0..255
    int lane = t & 63, w = t >> 6;
    int4 v = ((const int4*)binCnt)[t];
    int s0 = v.x, s1 = s0 + v.y, s2 = s1 + v.z, s3 = s2 + v.w;  // local inclusive
    int x = s3;
    #pragma unroll
    for (int off = 1; off < 64; off <<= 1) {
        int y = __shfl_up(x, off, 64);
        if (lane >= off) x += y;
    }
    if (lane == 63) wsum[w] = x;
    __syncthreads();
    int woff = 0;
    #pragma unroll
    for (int i = 0; i < 4; ++i) woff += (i < w) ? wsum[i] : 0;
    int texcl = woff + x - s3;           // exclusive prefix of this thread's 4 bins
    binStart[4*t+1] = texcl + s0;
    binStart[4*t+2] = texcl + s1;
    binStart[4*t+3] = texcl + s2;
    binStart[4*t+4] = texcl + s3;
    if (t == 0) binStart[0] = 0;
}

// ---------- Kernel 2b: scatter strokes into CSR order ----------
__global__ void binscatter_kernel(const float* __restrict__ loc, const int* __restrict__ binStart,
                                  int* __restrict__ binFill, float2* __restrict__ sxy,
                                  int* __restrict__ sid) {
    int i = blockIdx.x * 256 + threadIdx.x;
    if (i >= NS) return;
    float l0 = loc[i*2+0], l1 = loc[i*2+1];
    int b0 = min(max((int)(l0 * (1.0f/BINW)), 0), NBIN-1);
    int b1 = min(max((int)(l1 * (1.0f/BINW)), 0), NBIN-1);
    int b = b0*NBIN + b1;
    int pos = binStart[b] + atomicAdd(&binFill[b], 1);
    sxy[pos] = make_float2(l0, l1);
    sid[pos] = i;
}

// ---------- Kernel 3: per-cell top-20 via ballot compaction + rank selection ----------
// One wave per cell, 4 cells/block (grid = HC*HC/4 = 2601 exactly). Candidates
// with d<R^2 are ballot-compacted into wave-private LDS as (dist_bits<<32|idx)
// keys. Each lane computes its key's exact rank (# smaller keys) with an
// independent-iteration broadcast-read loop; ranks are a permutation (keys
// unique via idx low bits), so rank<20 lanes scatter straight to the output
// slot. Ascending distance, lower-index ties == jax.lax.top_k(-D, K) order.
// Exact: cnt>=20 inside radius R implies the global top-20 lie inside R.
__global__ void __launch_bounds__(256) topk_kernel(const float* __restrict__ loc,
                                                   const float* __restrict__ width,
                                                   const float2* __restrict__ sxy,
                                                   const int* __restrict__ sid,
                                                   const int* __restrict__ binStart,
                                                   int* __restrict__ idcs,
                                                   float* __restrict__ wk) {
    __shared__ unsigned long long sk[4][CAP];
    int w = threadIdx.x >> 6, lane = threadIdx.x & 63;
    int cell = blockIdx.x * 4 + w;                 // grid covers exactly HC*HC
    int ci = cell / HC, cj = cell - ci * HC;
    const float dc = 512.0f / 101.0f;              // linspace(0,512,102) step in fp32
    float c0 = (float)ci * dc;
    float c1 = (float)cj * dc;
    unsigned long long below = (1ull << lane) - 1ull;

    float R = 30.0f;                               // interior E[cnt] ~ 54
    int cnt = 0;
    for (int attempt = 0; attempt < 5; ++attempt) {
        float R2 = R * R;
        int base = 0;
        int by0 = max((int)((c0 - R) * (1.0f/BINW)), 0);
        int by1 = min((int)((c0 + R) * (1.0f/BINW)), NBIN-1);
        int bx0 = max((int)((c1 - R) * (1.0f/BINW)), 0);
        int bx1 = min((int)((c1 + R) * (1.0f/BINW)), NBIN-1);
        for (int by = by0; by <= by1; ++by) {
            int s = binStart[by*NBIN + bx0];
            int e = binStart[by*NBIN + bx1 + 1];   // bins in a row are contiguous
            for (int t0 = s; t0 < e; t0 += 64) {
                int t = t0 + lane;
                int tc = min(t, e - 1);
                float2 p = sxy[tc];
                float dx = c0 - p.x, dy = c1 - p.y;
                float d = dx*dx + dy*dy;
                bool pred = (t < e) && (d < R2);
                unsigned long long mask = __ballot(pred);
                int pos = base + __popcll(mask & below);
                if (pred && pos < CAP)
                    sk[w][pos] = ((unsigned long long)__float_as_uint(d) << 32)
                               | (unsigned int)sid[tc];
                base += __popcll(mask);
            }
        }
        cnt = base;
        if (cnt >= KK) break;                      // includes overflow -> fallback below
        R *= 1.6f;
    }
    WAVE_SYNC();

    if (cnt >= KK && cnt <= CAP) {
        if (cnt <= 64) {
            // common path (~92%): one key per lane
            unsigned long long k0 = (lane < cnt) ? sk[w][lane] : ~0ull;
            int r0 = 0;
            int j = 0;
            #pragma unroll 1
            for (; j + 4 <= cnt; j += 4) {
                unsigned long long a = sk[w][j],   b = sk[w][j+1];
                unsigned long long c = sk[w][j+2], d = sk[w][j+3];
                r0 += (int)(a < k0) + (int)(b < k0) + (int)(c < k0) + (int)(d < k0);
            }
            for (; j < cnt; ++j) r0 += (int)(sk[w][j] < k0);
            if (r0 < KK && lane < cnt) {
                int idx = (int)(unsigned int)(k0 & 0xffffffffull);
                idcs[cell*KK + r0] = idx;
                wk[cell*KK + r0]   = width[idx];
            }
        } else {
            // up to 3 keys per lane
            unsigned long long k0 = (lane       < cnt) ? sk[w][lane]       : ~0ull;
            unsigned long long k1 = (lane + 64  < cnt) ? sk[w][lane + 64]  : ~0ull;
            unsigned long long k2 = (lane + 128 < cnt) ? sk[w][lane + 128] : ~0ull;
            int r0 = 0, r1 = 0, r2 = 0;
            #pragma unroll 1
            for (int j = 0; j < cnt; ++j) {
                unsigned long long a = sk[w][j];
                r0 += (int)(a < k0); r1 += (int)(a < k1); r2 += (int)(a < k2);
            }
            if (r0 < KK && lane < cnt) {
                int idx = (int)(unsigned int)(k0 & 0xffffffffull);
                idcs[cell*KK + r0] = idx;  wk[cell*KK + r0] = width[idx];
            }
            if (r1 < KK && lane + 64 < cnt) {
                int idx = (int)(unsigned int)(k1 & 0xffffffffull);
                idcs[cell*KK + r1] = idx;  wk[cell*KK + r1] = width[idx];
            }
            if (r2 < KK && lane + 128 < cnt) {
                int idx = (int)(unsigned int)(k2 & 0xffffffffull);
                idcs[cell*KK + r2] = idx;  wk[cell*KK + r2] = width[idx];
            }
        }
    } else {
        // Exactness fallback (statistically never taken): serial top-K on lane 0.
        if (lane == 0) {
            float bd[KK]; int bi[KK];
            for (int k = 0; k < KK; ++k) { bd[k] = 3.4e38f; bi[k] = 0; }
            for (int n = 0; n < NS; ++n) {
                float dx = c0 - loc[n*2+0];
                float dy = c1 - loc[n*2+1];
                float d = dx*dx + dy*dy;
                if (d < bd[KK-1]) {
                    int p = KK - 1;
                    while (p > 0 && bd[p-1] > d) { bd[p] = bd[p-1]; bi[p] = bi[p-1]; --p; }
                    bd[p] = d; bi[p] = n;
                }
            }
            for (int k = 0; k < KK; ++k) {
                idcs[cell*KK + k] = bi[k];
                wk[cell*KK + k]   = width[bi[k]];
            }
        }
    }
}

// ---------- Kernel 4: full-res render ----------
// launch_bounds(256,4): grid is 4096 waves = 16 waves/CU max (4/SIMD), so cap
// VGPR at 128 and spend registers on unroll-4 gather overlap instead.
__global__ void __launch_bounds__(256, 4) render_kernel(const float* __restrict__ sdata,
                                                        const float4* __restrict__ ctab,
                                                        const int* __restrict__ idcs,
                                                        const float* __restrict__ wk,
                                                        float* __restrict__ out) {
    int x = blockIdx.x * 64 + threadIdx.x;   // wave = 64 contiguous x pixels
    int y = blockIdx.y * 4  + threadIdx.y;
    const float df = 512.0f / 511.0f;        // linspace(0,512,512) step in fp32
    float p0 = (float)y * df;                // H-coordinate
    float p1 = (float)x * df;                // W-coordinate
    int cy = (y * 51) >> 8;                  // floor(y*102/512), exact vs fp32 ref
    int cx = (x * 51) >> 8;

    // preload all 20 stroke indices (aligned: cell*20 ints = 80 B)
    const int4* mip = (const int4*)(idcs + (cy * HC + cx) * KK);
    int4 m0 = mip[0], m1 = mip[1], m2 = mip[2], m3 = mip[3], m4 = mip[4];
    int idxs[KK] = {m0.x,m0.y,m0.z,m0.w, m1.x,m1.y,m1.z,m1.w, m2.x,m2.y,m2.z,m2.w,
                    m3.x,m3.y,m3.z,m3.w, m4.x,m4.y,m4.z,m4.w};

    // jax.image.resize linear: half-pixel centers + edge-normalized == clamped bilinear
    const float sc = 102.0f / 512.0f;        // exact in fp32
    float iny = ((float)y + 0.5f) * sc - 0.5f;
    float inx = ((float)x + 0.5f) * sc - 0.5f;
    float y0f = floorf(iny), x0f = floorf(inx);
    float fy = iny - y0f, fx = inx - x0f;
    int y0 = min(max((int)y0f, 0), HC - 1);
    int y1 = min(max((int)y0f + 1, 0), HC - 1);
    int x0 = min(max((int)x0f, 0), HC - 1);
    int x1 = min(max((int)x0f + 1, 0), HC - 1);
    const float* w00 = wk + (y0 * HC + x0) * KK;
    const float* w01 = wk + (y0 * HC + x1) * KK;
    const float* w10 = wk + (y1 * HC + x0) * KK;
    const float* w11 = wk + (y1 * HC + x1) * KK;

    float m = -INFINITY, s = 0.0f;
    float a0 = 0.0f, a1 = 0.0f, a2 = 0.0f, wa = 0.0f;
    float D = INFINITY;

    #pragma unroll 4
    for (int k = 0; k < KK; ++k) {
        int idx = idxs[k];
        const float4* sp = (const float4*)(sdata + idx * 32);
        float4 f0 = sp[0], f1 = sp[1], f2 = sp[2], f3 = sp[3], f4 = sp[4];
        float4 i0 = sp[5], i1 = sp[6], i2 = sp[7];
        float4 cw = ctab[idx];
        float qx[10] = {f0.x, f0.z, f1.x, f1.z, f2.x, f2.z, f3.x, f3.z, f4.x, f4.z};
        float qy[10] = {f0.y, f0.w, f1.y, f1.w, f2.y, f2.w, f3.y, f3.w, f4.y, f4.w};
        float iv[9]  = {i0.x, i0.y, i0.z, i0.w, i1.x, i1.y, i1.z, i1.w, i2.x};
        float mink = INFINITY;
        #pragma unroll
        for (int sg = 0; sg < 9; ++sg) {
            float ax = qx[sg], ay = qy[sg];
            float bx = qx[sg+1] - ax, by = qy[sg+1] - ay;
            float pax = p0 - ax, pay = p1 - ay;
            float dot = bx * pax + by * pay;
            float t = dot * iv[sg];
            t = fminf(fmaxf(t, 0.0f), 1.0f);
            float ccx = ax + t * bx, ccy = ay + t * by;
            float ddx = p0 - ccx, ddy = p1 - ccy;
            float d = ddx * ddx + ddy * ddy;
            mink = fminf(mink, d);
        }
        D = fminf(D, mink);
        float z = 100000.0f / (1e-8f + mink);    // keep IEEE div: softmax exponent is
                                                 // rounding-sensitive, matches passing rounds
        float wkv = (1.0f - fy) * ((1.0f - fx) * w00[k] + fx * w01[k])
                  +          fy * ((1.0f - fx) * w10[k] + fx * w11[k]);
        // branchless online softmax: numerically identical to branchy form
        // (exp(0)==1 exactly on the taken side)
        float nm  = fmaxf(m, z);
        float scl = __expf(m - nm);              // m=-inf first iter -> 0
        float e   = __expf(z - nm);
        s  = s  * scl + e;
        a0 = a0 * scl + cw.x * e;
        a1 = a1 * scl + cw.y * e;
        a2 = a2 * scl + cw.z * e;
        wa = wa * scl + wkv  * e;
        m = nm;
    }
    float inv = 1.0f / s;
    float bs = wa * inv;
    float msk = 1.0f / (1.0f + __expf(-(bs - D)));   // sigmoid
    float o0 = a0 * inv * msk + (1.0f - msk) * 0.5f;
    float o1 = a1 * inv * msk + (1.0f - msk) * 0.5f;
    float o2 = a2 * inv * msk + (1.0f - msk) * 0.5f;
    int base = (y * 512 + x) * 3;
    out[base+0] = o0;
    out[base+1] = o1;
    out[base+2] = o2;
}

extern "C" void kernel_launch(void* const* d_in, const int* in_sizes, int n_in,
                              void* d_out, int out_size, void* d_ws, size_t ws_size,
                              hipStream_t stream) {
    const float* cs    = (const float*)d_in[0];  // curve_s (5000,2)
    const float* ce    = (const float*)d_in[1];  // curve_e (5000,2)
    const float* cc    = (const float*)d_in[2];  // curve_c (5000,2)
    const float* color = (const float*)d_in[3];  // color   (5000,3)
    const float* loc   = (const float*)d_in[4];  // location(5000,2)
    const float* width = (const float*)d_in[5];  // width   (5000,1)
    float* out = (float*)d_out;

    char* p = (char*)d_ws;
    float*  sdata    = (float*)p;                 p += NS * 32 * sizeof(float);       // 640000
    float4* ctab     = (float4*)p;                p += NS * sizeof(float4);           // 80000
    int*    idcs     = (int*)p;                   p += (size_t)HC*HC*KK*sizeof(int);  // 832320
    float*  wk       = (float*)p;                 p += (size_t)HC*HC*KK*sizeof(float);// 832320
    int*    binCnt   = (int*)p;                   p += NBIN*NBIN*sizeof(int);         // 4096
    int*    binFill  = (int*)p;                   p += NBIN*NBIN*sizeof(int);         // 4096
    int*    binStart = (int*)p;                   p += 4112;                          // 1025 ints + pad
    float2* sxy      = (float2*)p;                p += NS * sizeof(float2);           // 40000
    int*    sid      = (int*)p;                   /* 20000 */

    hipMemsetAsync(binCnt, 0, 2 * NBIN * NBIN * sizeof(int), stream);  // binCnt + binFill

    prep_kernel      <<<(NS + 255) / 256, 256, 0, stream>>>(cs, ce, cc, loc, color, width,
                                                            sdata, ctab, binCnt);
    binscan_kernel   <<<1, 256, 0, stream>>>(binCnt, binStart);
    binscatter_kernel<<<(NS + 255) / 256, 256, 0, stream>>>(loc, binStart, binFill, sxy, sid);
    topk_kernel      <<<(HC*HC)/4, 256, 0, stream>>>(loc, width, sxy, sid, binStart, idcs, wk);
    render_kernel    <<<dim3(512/64, 512/4), dim3(64, 4), 0, stream>>>(sdata, ctab, idcs, wk, out);
}